// Round 1
// baseline (144.892 us; speedup 1.0000x reference)
//
#include <hip/hip_runtime.h>
#include <math.h>

// ---------------------------------------------------------------------------
// The reference is a chain of linear resampling ops. We collapse each chain
// into a single matrix on-device (tables kernel), then apply:
//   x_out[bc] = Mx (103x64) @ x[bc] (64)
//   y_out[bc] = Ry (44x32) @ y[bc] (32x32) @ Cy^T (32x30)
//   w_out[bc][i][j] = w[bc][idx[i]][idx[j]]  (nearest gather, s = 1/2.976744)
// ---------------------------------------------------------------------------

struct Step { int mode; int out; int ac; }; // mode: 0=nearest(n/out), 1=linear, 2=cubic

__device__ const Step X_STEPS[11] = {
    {0,16,0},{0,32,0},{0,20,0},{0,80,0},
    {1,16,0},{1,32,0},{1,24,1},{1,72,1},
    {0,108,0},{1,129,0},{1,103,1}};

__device__ const Step R_STEPS[23] = {
    {0,16,0},{0,32,0},{0,20,0},{0,80,0},{0,16,0},{0,32,0},
    {1,16,0},{1,32,0},{1,20,0},{1,80,0},{1,16,1},{1,32,1},
    {2,16,0},{2,32,0},{2,20,0},{2,80,0},{2,16,1},{2,32,1},
    {0,51,0},{1,102,0},{1,51,1},{2,40,0},{2,44,1}};

__device__ const Step C_STEPS[23] = {
    {0,16,0},{0,32,0},{0,20,0},{0,80,0},{0,24,0},{0,72,0},
    {1,16,0},{1,32,0},{1,20,0},{1,80,0},{1,24,1},{1,72,1},
    {2,16,0},{2,32,0},{2,20,0},{2,80,0},{2,24,1},{2,72,1},
    {0,144,0},{1,172,0},{1,68,1},{2,61,0},{2,30,1}};

// Tap computation faithful to the reference (fp32 semantics; nearest must be
// bit-exact: single fp32 multiply of fp32(o) by fp32(n/out), then floor).
__device__ inline void taps_for(int mode, int ac, int o, int n, int out,
                                int* idx, float* w) {
    if (mode == 0) {
        float s = (float)((double)n / (double)out);
        int i = (int)floorf((float)o * s);
        i = min(max(i, 0), n - 1);
        idx[0] = i; w[0] = 1.0f;
        return;
    }
    float src;
    if (ac) {
        float s = (out > 1) ? (float)((double)(n - 1) / (double)(out - 1)) : 0.0f;
        src = (float)o * s;
    } else {
        float s = (float)((double)n / (double)out);
        src = ((float)o + 0.5f) * s - 0.5f;
    }
    if (mode == 1) {
        src = fmaxf(src, 0.0f);
        int i0 = min(max((int)floorf(src), 0), n - 1);
        int i1 = min(i0 + 1, n - 1);
        float t = src - (float)i0;
        idx[0] = i0; w[0] = 1.0f - t;
        idx[1] = i1; w[1] = t;
        return;
    }
    // cubic, A = -0.75, src NOT clamped
    const float A = -0.75f;
    float fi = floorf(src);
    int i = (int)fi;
    float t = src - fi;
    float u;
    u = t + 1.0f; w[0] = ((A * u - 5.0f * A) * u + 8.0f * A) * u - 4.0f * A;
    u = t;        w[1] = ((A + 2.0f) * u - (A + 3.0f)) * u * u + 1.0f;
    u = 1.0f - t; w[2] = ((A + 2.0f) * u - (A + 3.0f)) * u * u + 1.0f;
    u = 2.0f - t; w[3] = ((A * u - 5.0f * A) * u + 8.0f * A) * u - 4.0f * A;
    for (int k = 0; k < 4; k++) idx[k] = min(max(i + k - 1, 0), n - 1);
}

#define ARENA_CAP 15168   // floats; max consecutive (n_in+n_out)*NC = (108+129)*64
#define MAX_OUT   172

template <int NC>
__device__ void run_chain(const Step* steps, int nsteps,
                          float* arena, short* s_idx, float* s_w,
                          float* outg) {
    const int tid = threadIdx.x;
    const int nthr = blockDim.x;
    int n = NC;
    int cur_off = 0;
    // identity NC x NC
    for (int e = tid; e < NC * NC; e += nthr)
        arena[e] = ((e / NC) == (e % NC)) ? 1.0f : 0.0f;
    __syncthreads();
    for (int s = 0; s < nsteps; s++) {
        const int mode = steps[s].mode;
        const int ac   = steps[s].ac;
        const int out  = steps[s].out;
        const int nt   = (mode == 0) ? 1 : ((mode == 1) ? 2 : 4);
        const int nxt_off = (cur_off == 0) ? (ARENA_CAP - out * NC) : 0;
        // per-output-row taps into LDS
        for (int o = tid; o < out; o += nthr) {
            int idx[4]; float w[4];
            taps_for(mode, ac, o, n, out, idx, w);
            for (int k = 0; k < nt; k++) {
                s_idx[o * 4 + k] = (short)idx[k];
                s_w[o * 4 + k] = w[k];
            }
        }
        __syncthreads();
        // compose: newM[o][j] = sum_k w_k * M[idx_k][j]
        for (int e = tid; e < out * NC; e += nthr) {
            int o = e / NC, j = e % NC;
            float acc = 0.0f;
            for (int k = 0; k < nt; k++)
                acc += s_w[o * 4 + k] * arena[cur_off + (int)s_idx[o * 4 + k] * NC + j];
            arena[nxt_off + e] = acc;
        }
        __syncthreads();
        cur_off = nxt_off;
        n = out;
    }
    for (int e = tid; e < n * NC; e += nthr) outg[e] = arena[cur_off + e];
}

__global__ __launch_bounds__(512) void build_tables(float* __restrict__ mx,
                                                    float* __restrict__ ry,
                                                    float* __restrict__ cy) {
    __shared__ float arena[ARENA_CAP];
    __shared__ short s_idx[MAX_OUT * 4];
    __shared__ float s_w[MAX_OUT * 4];
    if (blockIdx.x == 0)      run_chain<64>(X_STEPS, 11, arena, s_idx, s_w, mx);
    else if (blockIdx.x == 1) run_chain<32>(R_STEPS, 23, arena, s_idx, s_w, ry);
    else                      run_chain<32>(C_STEPS, 23, arena, s_idx, s_w, cy);
}

// ---- x: out[bc][o] = sum_j Mx[o][j] * x[bc][j]   (2048 x 103, j<64) ----
__global__ __launch_bounds__(128) void apply_x(const float* __restrict__ x,
                                               const float* __restrict__ mx,
                                               float* __restrict__ out) {
    const int bc = blockIdx.x;
    __shared__ float row[64];
    const int tid = threadIdx.x;
    if (tid < 64) row[tid] = x[bc * 64 + tid];
    __syncthreads();
    if (tid < 103) {
        const float* m = mx + tid * 64;
        float acc = 0.0f;
#pragma unroll
        for (int j = 0; j < 64; j++) acc += m[j] * row[j];
        out[bc * 103 + tid] = acc;
    }
}

// ---- y: out[bc] = Ry (44x32) @ y[bc] (32x32) @ Cy^T (Cy is 30x32) ----
__global__ __launch_bounds__(256) void apply_y(const float* __restrict__ y,
                                               const float* __restrict__ ryg,
                                               const float* __restrict__ cyg,
                                               float* __restrict__ out) {
    const int bc = blockIdx.x;
    __shared__ float yin[32 * 32];
    __shared__ float T[32 * 30];
    __shared__ float ry[44 * 32];
    __shared__ float cy[30 * 32];
    const int tid = threadIdx.x;
    for (int e = tid; e < 1024; e += 256) yin[e] = y[bc * 1024 + e];
    for (int e = tid; e < 44 * 32; e += 256) ry[e] = ryg[e];
    for (int e = tid; e < 30 * 32; e += 256) cy[e] = cyg[e];
    __syncthreads();
    // T[r][c'] = sum_c yin[r][c] * Cy[c'][c]
    for (int e = tid; e < 32 * 30; e += 256) {
        int r = e / 30, cp = e % 30;
        float acc = 0.0f;
#pragma unroll
        for (int c = 0; c < 32; c++) acc += yin[r * 32 + c] * cy[cp * 32 + c];
        T[e] = acc;
    }
    __syncthreads();
    // out[o][c'] = sum_r Ry[o][r] * T[r][c']
    for (int e = tid; e < 44 * 30; e += 256) {
        int o = e / 30, cp = e % 30;
        float acc = 0.0f;
#pragma unroll
        for (int r = 0; r < 32; r++) acc += ry[o * 32 + r] * T[r * 30 + cp];
        out[bc * 1320 + e] = acc;
    }
}

// ---- w: nearest gather 24x24 -> 71x71, scale = fp32(1/2.976744) ----
__global__ __launch_bounds__(256) void apply_w(const float* __restrict__ w,
                                               float* __restrict__ out) {
    const int bc = blockIdx.x;
    __shared__ float win[24 * 24];
    __shared__ int idx[71];
    const int tid = threadIdx.x;
    for (int e = tid; e < 576; e += 256) win[e] = w[bc * 576 + e];
    if (tid < 71) {
        const float s = (float)(1.0 / 2.976744);
        idx[tid] = min(max((int)floorf((float)tid * s), 0), 23);
    }
    __syncthreads();
    for (int e = tid; e < 71 * 71; e += 256) {
        int i = e / 71, j = e - i * 71;
        out[bc * 5041 + e] = win[idx[i] * 24 + idx[j]];
    }
}

extern "C" void kernel_launch(void* const* d_in, const int* in_sizes, int n_in,
                              void* d_out, int out_size, void* d_ws, size_t ws_size,
                              hipStream_t stream) {
    (void)in_sizes; (void)n_in; (void)out_size; (void)ws_size;
    const float* x = (const float*)d_in[0];   // (8,256,64)
    const float* y = (const float*)d_in[1];   // (8,256,32,32)
    const float* w = (const float*)d_in[2];   // (8,256,24,24)
    float* out = (float*)d_out;
    float* ws = (float*)d_ws;

    float* mx = ws;            // 103*64 = 6592
    float* ry = ws + 6592;     // 44*32  = 1408
    float* cy = ws + 8000;     // 30*32  = 960

    const int X_OFF = 0;
    const int Y_OFF = 2048 * 103;                 // 210944
    const int W_OFF = Y_OFF + 2048 * 44 * 30;     // 2914304

    build_tables<<<3, 512, 0, stream>>>(mx, ry, cy);
    apply_x<<<2048, 128, 0, stream>>>(x, mx, out + X_OFF);
    apply_y<<<2048, 256, 0, stream>>>(y, ry, cy, out + Y_OFF);
    apply_w<<<2048, 256, 0, stream>>>(w, out + W_OFF);
}

// Round 2
// 132.220 us; speedup vs baseline: 1.0958x; 1.0958x over previous
//
#include <hip/hip_runtime.h>
#include <math.h>

// ---------------------------------------------------------------------------
// Chain of linear resampling ops collapsed into matrices (built on device):
//   x_out[bc] = Mx (103x64) @ x[bc] (64)            -> stored transposed MxT
//   y_out[bc] = Ry (44x32) @ y[bc] (32x32) @ Cy^T   (Cy is 30x32)
//   w_out[bc][i][j] = w[bc][idx[i]][idx[j]]         (nearest, s = 1/2.976744)
// One build kernel (3 blocks) + one fused apply kernel (2048 blocks).
// ---------------------------------------------------------------------------

struct Step { int mode; int out; int ac; }; // mode: 0=nearest(n/out), 1=linear, 2=cubic

__device__ const Step X_STEPS[11] = {
    {0,16,0},{0,32,0},{0,20,0},{0,80,0},
    {1,16,0},{1,32,0},{1,24,1},{1,72,1},
    {0,108,0},{1,129,0},{1,103,1}};

__device__ const Step R_STEPS[23] = {
    {0,16,0},{0,32,0},{0,20,0},{0,80,0},{0,16,0},{0,32,0},
    {1,16,0},{1,32,0},{1,20,0},{1,80,0},{1,16,1},{1,32,1},
    {2,16,0},{2,32,0},{2,20,0},{2,80,0},{2,16,1},{2,32,1},
    {0,51,0},{1,102,0},{1,51,1},{2,40,0},{2,44,1}};

__device__ const Step C_STEPS[23] = {
    {0,16,0},{0,32,0},{0,20,0},{0,80,0},{0,24,0},{0,72,0},
    {1,16,0},{1,32,0},{1,20,0},{1,80,0},{1,24,1},{1,72,1},
    {2,16,0},{2,32,0},{2,20,0},{2,80,0},{2,24,1},{2,72,1},
    {0,144,0},{1,172,0},{1,68,1},{2,61,0},{2,30,1}};

// Tap computation faithful to the reference (fp32 semantics; nearest must be
// bit-exact: single fp32 multiply of fp32(o) by fp32(n/out), then floor).
__device__ inline void taps_for(int mode, int ac, int o, int n, int out,
                                int* idx, float* w) {
    if (mode == 0) {
        float s = (float)((double)n / (double)out);
        int i = (int)floorf((float)o * s);
        i = min(max(i, 0), n - 1);
        idx[0] = i; w[0] = 1.0f;
        return;
    }
    float src;
    if (ac) {
        float s = (out > 1) ? (float)((double)(n - 1) / (double)(out - 1)) : 0.0f;
        src = (float)o * s;
    } else {
        float s = (float)((double)n / (double)out);
        src = ((float)o + 0.5f) * s - 0.5f;
    }
    if (mode == 1) {
        src = fmaxf(src, 0.0f);
        int i0 = min(max((int)floorf(src), 0), n - 1);
        int i1 = min(i0 + 1, n - 1);
        float t = src - (float)i0;
        idx[0] = i0; w[0] = 1.0f - t;
        idx[1] = i1; w[1] = t;
        return;
    }
    const float A = -0.75f;
    float fi = floorf(src);
    int i = (int)fi;
    float t = src - fi;
    float u;
    u = t + 1.0f; w[0] = ((A * u - 5.0f * A) * u + 8.0f * A) * u - 4.0f * A;
    u = t;        w[1] = ((A + 2.0f) * u - (A + 3.0f)) * u * u + 1.0f;
    u = 1.0f - t; w[2] = ((A + 2.0f) * u - (A + 3.0f)) * u * u + 1.0f;
    u = 2.0f - t; w[3] = ((A * u - 5.0f * A) * u + 8.0f * A) * u - 4.0f * A;
    for (int k = 0; k < 4; k++) idx[k] = min(max(i + k - 1, 0), n - 1);
}

#define ARENA_CAP 15168   // floats; max consecutive (n_in+n_out)*NC = (108+129)*64
#define MAX_ROWS  1216    // >= total output rows across one chain's steps (C: 1207)

template <int NC>
__device__ void run_chain(const Step* steps, int nsteps,
                          float* arena, short* s_idx, float* s_w,
                          float* outg, int transpose) {
    const int tid = threadIdx.x;
    const int nthr = blockDim.x;
    // ---- phase 1: ALL taps (data-independent; one barrier total) ----
    {
        int n = NC, roff = 0;
        for (int s = 0; s < nsteps; s++) {
            const int mode = steps[s].mode, ac = steps[s].ac, out = steps[s].out;
            const int nt = (mode == 0) ? 1 : ((mode == 1) ? 2 : 4);
            for (int o = tid; o < out; o += nthr) {
                int idx[4]; float w[4];
                taps_for(mode, ac, o, n, out, idx, w);
                for (int k = 0; k < nt; k++) {
                    s_idx[(roff + o) * 4 + k] = (short)idx[k];
                    s_w[(roff + o) * 4 + k] = w[k];
                }
            }
            n = out; roff += out;
        }
    }
    // identity NC x NC
    for (int e = tid; e < NC * NC; e += nthr)
        arena[e] = ((e / NC) == (e % NC)) ? 1.0f : 0.0f;
    __syncthreads();
    // ---- phase 2: compose (one barrier per step) ----
    int n = NC, cur = 0, roff = 0;
    for (int s = 0; s < nsteps; s++) {
        const int mode = steps[s].mode, out = steps[s].out;
        const int nt = (mode == 0) ? 1 : ((mode == 1) ? 2 : 4);
        const int nxt = (cur == 0) ? (ARENA_CAP - out * NC) : 0;
        for (int e = tid; e < out * NC; e += nthr) {
            int o = e / NC, j = e - o * NC;
            float acc = 0.0f;
            for (int k = 0; k < nt; k++)
                acc += s_w[(roff + o) * 4 + k] *
                       arena[cur + (int)s_idx[(roff + o) * 4 + k] * NC + j];
            arena[nxt + e] = acc;
        }
        __syncthreads();
        cur = nxt; n = out; roff += out;
    }
    if (transpose) {
        for (int e = tid; e < n * NC; e += nthr) {
            int o = e / NC, j = e - o * NC;
            outg[j * n + o] = arena[cur + e];
        }
    } else {
        for (int e = tid; e < n * NC; e += nthr) outg[e] = arena[cur + e];
    }
}

__global__ __launch_bounds__(512) void build_tables(float* __restrict__ mxT,
                                                    float* __restrict__ ry,
                                                    float* __restrict__ cy) {
    __shared__ float arena[ARENA_CAP];
    __shared__ short s_idx[MAX_ROWS * 4];
    __shared__ float s_w[MAX_ROWS * 4];
    if (blockIdx.x == 0)      run_chain<64>(X_STEPS, 11, arena, s_idx, s_w, mxT, 1);
    else if (blockIdx.x == 1) run_chain<32>(R_STEPS, 23, arena, s_idx, s_w, ry, 0);
    else                      run_chain<32>(C_STEPS, 23, arena, s_idx, s_w, cy, 0);
}

// ---------------------------------------------------------------------------
// Fused apply: one block per (b,c) image.
// ---------------------------------------------------------------------------
#define X_OFF 0
#define Y_OFF 210944            // 2048*103
#define W_OFF 2914304           // Y_OFF + 2048*44*30

__global__ __launch_bounds__(256) void fused_apply(
        const float* __restrict__ x, const float* __restrict__ y,
        const float* __restrict__ w, const float* __restrict__ mxT,
        const float* __restrict__ ryg, const float* __restrict__ cyg,
        float* __restrict__ out) {
    const int bc = blockIdx.x;
    const int tid = threadIdx.x;
    __shared__ float yin[32 * 33];   // padded stride 33 (bank-conflict-free)
    __shared__ float s_cy[30 * 33];
    __shared__ float s_ry[44 * 33];
    __shared__ float T[32 * 30];
    __shared__ float win[576];
    __shared__ float xrow[64];
    __shared__ int   widx[71];

    const float* ybc = y + bc * 1024;
    const float* wbc = w + bc * 576;
    for (int e = tid; e < 1024; e += 256) { int r = e >> 5, c = e & 31; yin[r * 33 + c] = ybc[e]; }
    for (int e = tid; e < 1408; e += 256) { int o = e >> 5, r = e & 31; s_ry[o * 33 + r] = ryg[e]; }
    for (int e = tid; e < 960;  e += 256) { int p = e >> 5, c = e & 31; s_cy[p * 33 + c] = cyg[e]; }
    for (int e = tid; e < 576;  e += 256) win[e] = wbc[e];
    if (tid < 64) xrow[tid] = x[bc * 64 + tid];
    if (tid < 71) {
        const float s = (float)(1.0 / 2.976744);
        widx[tid] = min(max((int)floorf((float)tid * s), 0), 23);
    }
    __syncthreads();

    // T[r][cp] = sum_c yin[r][c] * Cy[cp][c]
    for (int e = tid; e < 960; e += 256) {
        int r = e / 30, cp = e - r * 30;
        const float* yr = &yin[r * 33];
        const float* cr = &s_cy[cp * 33];
        float acc = 0.0f;
#pragma unroll
        for (int c = 0; c < 32; c++) acc += yr[c] * cr[c];
        T[e] = acc;
    }
    __syncthreads();

    // y out: out[o][cp] = sum_r Ry[o][r] * T[r][cp]
    float* oy = out + Y_OFF + bc * 1320;
    for (int e = tid; e < 1320; e += 256) {
        int o = e / 30, cp = e - o * 30;
        const float* rr = &s_ry[o * 33];
        float acc = 0.0f;
#pragma unroll
        for (int r = 0; r < 32; r++) acc += rr[r] * T[r * 30 + cp];
        oy[e] = acc;
    }

    // x out: coalesced via transposed Mx
    if (tid < 103) {
        float acc = 0.0f;
#pragma unroll
        for (int j = 0; j < 64; j++) acc += mxT[j * 103 + tid] * xrow[j];
        out[X_OFF + bc * 103 + tid] = acc;
    }

    // w out: nearest gather 24x24 -> 71x71
    float* ow = out + W_OFF + bc * 5041;
    for (int e = tid; e < 5041; e += 256) {
        int i = e / 71, j = e - i * 71;
        ow[e] = win[widx[i] * 24 + widx[j]];
    }
}

extern "C" void kernel_launch(void* const* d_in, const int* in_sizes, int n_in,
                              void* d_out, int out_size, void* d_ws, size_t ws_size,
                              hipStream_t stream) {
    (void)in_sizes; (void)n_in; (void)out_size; (void)ws_size;
    const float* x = (const float*)d_in[0];   // (8,256,64)
    const float* y = (const float*)d_in[1];   // (8,256,32,32)
    const float* w = (const float*)d_in[2];   // (8,256,24,24)
    float* out = (float*)d_out;
    float* ws = (float*)d_ws;

    float* mxT = ws;           // 64*103 = 6592 (transposed)
    float* ry  = ws + 6592;    // 44*32  = 1408
    float* cy  = ws + 8000;    // 30*32  = 960

    build_tables<<<3, 512, 0, stream>>>(mxT, ry, cy);
    fused_apply<<<2048, 256, 0, stream>>>(x, y, w, mxT, ry, cy, out);
}

// Round 6
// 100.305 us; speedup vs baseline: 1.4445x; 1.3182x over previous
//
#include <hip/hip_runtime.h>
#include <math.h>

// ---------------------------------------------------------------------------
// The reference is a fixed chain of linear resampling operators. All three
// chains collapse to constant matrices / index tables, which we compute
// entirely at COMPILE TIME (constexpr, one template instantiation per step so
// each constant evaluation stays under clang's step limit):
//   x_out[bc] = Mx (103x64) @ x[bc]              (stored transposed: MxT)
//   y_out[bc] = Ry (44x32) @ y[bc] @ Cy^T        (Cy is 30x32)
//   w_out[bc][i][j] = w[bc][idx[i]][idx[j]]      (nearest, s = fp32(1/2.976744))
// Runtime = ONE fused memory-bound kernel, 2048 blocks (one per (b,c) image).
// ---------------------------------------------------------------------------

struct Step { int mode; int out; int ac; }; // mode: 0=nearest(n/out), 1=linear, 2=cubic

constexpr Step X_STEPS[11] = {
    {0,16,0},{0,32,0},{0,20,0},{0,80,0},
    {1,16,0},{1,32,0},{1,24,1},{1,72,1},
    {0,108,0},{1,129,0},{1,103,1}};

constexpr Step R_STEPS[23] = {
    {0,16,0},{0,32,0},{0,20,0},{0,80,0},{0,16,0},{0,32,0},
    {1,16,0},{1,32,0},{1,20,0},{1,80,0},{1,16,1},{1,32,1},
    {2,16,0},{2,32,0},{2,20,0},{2,80,0},{2,16,1},{2,32,1},
    {0,51,0},{1,102,0},{1,51,1},{2,40,0},{2,44,1}};

constexpr Step C_STEPS[23] = {
    {0,16,0},{0,32,0},{0,20,0},{0,80,0},{0,24,0},{0,72,0},
    {1,16,0},{1,32,0},{1,20,0},{1,80,0},{1,24,1},{1,72,1},
    {2,16,0},{2,32,0},{2,20,0},{2,80,0},{2,24,1},{2,72,1},
    {0,144,0},{1,172,0},{1,68,1},{2,61,0},{2,30,1}};

// ---- constexpr fp32 helpers (correctly-rounded per op, same as device) ----
constexpr int ifloor(float x) { int i = (int)x; return ((float)i > x) ? i - 1 : i; }
constexpr int iclamp(int v, int lo, int hi) { return v < lo ? lo : (v > hi ? hi : v); }

struct Taps { int idx[4]; float w[4]; int nt; };

// Faithful to the reference fp32 op sequence (nearest must be bit-exact:
// single fp32 multiply of fp32(o) by fp32(n/out), then floor).
constexpr Taps taps_for(int mode, int ac, int o, int n, int out) {
    Taps t{};
    if (mode == 0) {
        float s = (float)((double)n / (double)out);
        t.idx[0] = iclamp(ifloor((float)o * s), 0, n - 1);
        t.w[0] = 1.0f; t.nt = 1;
        return t;
    }
    float src = 0.0f;
    if (ac) {
        float s = (out > 1) ? (float)((double)(n - 1) / (double)(out - 1)) : 0.0f;
        src = (float)o * s;
    } else {
        float s = (float)((double)n / (double)out);
        src = ((float)o + 0.5f) * s - 0.5f;
    }
    if (mode == 1) {
        src = (src > 0.0f) ? src : 0.0f;
        int i0 = iclamp(ifloor(src), 0, n - 1);
        int i1 = (i0 + 1 < n - 1) ? (i0 + 1) : (n - 1);
        float tt = src - (float)i0;
        t.idx[0] = i0; t.w[0] = 1.0f - tt;
        t.idx[1] = i1; t.w[1] = tt;
        t.nt = 2;
        return t;
    }
    const float A = -0.75f;
    int i = ifloor(src);
    float tt = src - (float)i;
    float u;
    u = tt + 1.0f; t.w[0] = ((A * u - 5.0f * A) * u + 8.0f * A) * u - 4.0f * A;
    u = tt;        t.w[1] = ((A + 2.0f) * u - (A + 3.0f)) * u * u + 1.0f;
    u = 1.0f - tt; t.w[2] = ((A + 2.0f) * u - (A + 3.0f)) * u * u + 1.0f;
    u = 2.0f - tt; t.w[3] = ((A * u - 5.0f * A) * u + 8.0f * A) * u - 4.0f * A;
    for (int k = 0; k < 4; k++) t.idx[k] = iclamp(i + k - 1, 0, n - 1);
    t.nt = 4;
    return t;
}

struct Mat { float v[172 * 64]; int rows, cols; };

constexpr Mat identity(int n) {
    Mat m{}; m.rows = n; m.cols = n;
    for (int i = 0; i < n; i++) m.v[i * n + i] = 1.0f;
    return m;
}

// newM[o][j] = sum_k w_k * M[idx_k][j]
constexpr Mat compose(const Mat& src, Step st) {
    Mat d{};
    const int NC = src.cols, n = src.rows, out = st.out;
    d.rows = out; d.cols = NC;
    for (int o = 0; o < out; o++) {
        Taps t = taps_for(st.mode, st.ac, o, n, out);
        for (int j = 0; j < NC; j++) {
            float acc = 0.0f;
            for (int k = 0; k < t.nt; k++)
                acc += t.w[k] * src.v[t.idx[k] * NC + j];
            d.v[o * NC + j] = acc;
        }
    }
    return d;
}

// One template instantiation per step => separate constexpr evaluations.
template <int S> struct XC { static constexpr Mat m = compose(XC<S - 1>::m, X_STEPS[S]); };
template <> struct XC<-1>  { static constexpr Mat m = identity(64); };
template <int S> struct RC { static constexpr Mat m = compose(RC<S - 1>::m, R_STEPS[S]); };
template <> struct RC<-1>  { static constexpr Mat m = identity(32); };
template <int S> struct CC { static constexpr Mat m = compose(CC<S - 1>::m, C_STEPS[S]); };
template <> struct CC<-1>  { static constexpr Mat m = identity(32); };

struct TblMxT { alignas(16) float v[64 * 103]; };
constexpr TblMxT make_mxT() {
    TblMxT t{};
    for (int o = 0; o < 103; o++)
        for (int j = 0; j < 64; j++)
            t.v[j * 103 + o] = XC<10>::m.v[o * 64 + j];
    return t;
}
struct TblRy { alignas(16) float v[44 * 32]; };
constexpr TblRy make_ry() {
    TblRy t{};
    for (int e = 0; e < 44 * 32; e++) t.v[e] = RC<22>::m.v[e];
    return t;
}
struct TblCy { alignas(16) float v[30 * 32]; };
constexpr TblCy make_cy() {
    TblCy t{};
    for (int e = 0; e < 30 * 32; e++) t.v[e] = CC<22>::m.v[e];
    return t;
}
struct TblWidx { int v[71]; };
constexpr TblWidx make_widx() {
    TblWidx t{};
    const float s = (float)(1.0 / 2.976744);
    for (int i = 0; i < 71; i++) t.v[i] = iclamp(ifloor((float)i * s), 0, 23);
    return t;
}

__device__ const TblMxT  g_mxT  = make_mxT();
__device__ const TblRy   g_ry   = make_ry();
__device__ const TblCy   g_cy   = make_cy();
__device__ const TblWidx g_widx = make_widx();

// ---------------------------------------------------------------------------
#define X_OFF 0
#define Y_OFF 210944            // 2048*103
#define W_OFF 2914304           // Y_OFF + 2048*44*30

__global__ __launch_bounds__(256) void fused_apply(
        const float* __restrict__ x, const float* __restrict__ y,
        const float* __restrict__ w, float* __restrict__ out) {
    const int bc = blockIdx.x;
    const int tid = threadIdx.x;
    __shared__ float yin[32 * 33];   // padded stride 33 (bank-conflict-free)
    __shared__ float s_cy[30 * 33];
    __shared__ float s_ry[44 * 33];
    __shared__ float T[32 * 30];
    __shared__ float win[576];
    __shared__ float xrow[64];
    __shared__ int   widx[71];

    const float* ybc = y + bc * 1024;
    const float* wbc = w + bc * 576;

    { // yin: 1024 floats = 256 float4, one per thread
        float4 v = reinterpret_cast<const float4*>(ybc)[tid];
        int r = tid >> 3, c = (tid & 7) * 4;
        yin[r * 33 + c + 0] = v.x; yin[r * 33 + c + 1] = v.y;
        yin[r * 33 + c + 2] = v.z; yin[r * 33 + c + 3] = v.w;
    }
    for (int e = tid; e < 352; e += 256) { // ry: 1408 floats
        float4 v = reinterpret_cast<const float4*>(g_ry.v)[e];
        int o = e >> 3, r = (e & 7) * 4;
        s_ry[o * 33 + r + 0] = v.x; s_ry[o * 33 + r + 1] = v.y;
        s_ry[o * 33 + r + 2] = v.z; s_ry[o * 33 + r + 3] = v.w;
    }
    if (tid < 240) { // cy: 960 floats
        float4 v = reinterpret_cast<const float4*>(g_cy.v)[tid];
        int p = tid >> 3, c = (tid & 7) * 4;
        s_cy[p * 33 + c + 0] = v.x; s_cy[p * 33 + c + 1] = v.y;
        s_cy[p * 33 + c + 2] = v.z; s_cy[p * 33 + c + 3] = v.w;
    }
    if (tid < 144) { // win: 576 floats
        float4 v = reinterpret_cast<const float4*>(wbc)[tid];
        win[tid * 4 + 0] = v.x; win[tid * 4 + 1] = v.y;
        win[tid * 4 + 2] = v.z; win[tid * 4 + 3] = v.w;
    }
    if (tid < 64) xrow[tid] = x[bc * 64 + tid];
    if (tid < 71) widx[tid] = g_widx.v[tid];
    __syncthreads();

    // T[r][cp] = sum_c yin[r][c] * Cy[cp][c]
    for (int e = tid; e < 960; e += 256) {
        int r = e / 30, cp = e - r * 30;
        const float* yr = &yin[r * 33];
        const float* cr = &s_cy[cp * 33];
        float acc = 0.0f;
#pragma unroll
        for (int c = 0; c < 32; c++) acc += yr[c] * cr[c];
        T[e] = acc;
    }
    __syncthreads();

    // y out: out[o][cp] = sum_r Ry[o][r] * T[r][cp]
    float* oy = out + Y_OFF + bc * 1320;
    for (int e = tid; e < 1320; e += 256) {
        int o = e / 30, cp = e - o * 30;
        const float* rr = &s_ry[o * 33];
        float acc = 0.0f;
#pragma unroll
        for (int r = 0; r < 32; r++) acc += rr[r] * T[r * 30 + cp];
        oy[e] = acc;
    }

    // x out: coalesced via transposed Mx (L2-resident .rodata)
    if (tid < 103) {
        float acc = 0.0f;
#pragma unroll
        for (int j = 0; j < 64; j++) acc += g_mxT.v[j * 103 + tid] * xrow[j];
        out[X_OFF + bc * 103 + tid] = acc;
    }

    // w out: nearest gather 24x24 -> 71x71
    float* ow = out + W_OFF + bc * 5041;
    for (int e = tid; e < 5041; e += 256) {
        int i = e / 71, j = e - i * 71;
        ow[e] = win[widx[i] * 24 + widx[j]];
    }
}

extern "C" void kernel_launch(void* const* d_in, const int* in_sizes, int n_in,
                              void* d_out, int out_size, void* d_ws, size_t ws_size,
                              hipStream_t stream) {
    (void)in_sizes; (void)n_in; (void)out_size; (void)d_ws; (void)ws_size;
    const float* x = (const float*)d_in[0];   // (8,256,64)
    const float* y = (const float*)d_in[1];   // (8,256,32,32)
    const float* w = (const float*)d_in[2];   // (8,256,24,24)
    float* out = (float*)d_out;
    fused_apply<<<2048, 256, 0, stream>>>(x, y, w, out);
}